// Round 7
// baseline (196.742 us; speedup 1.0000x reference)
//
#include <hip/hip_runtime.h>
#include <math.h>

#define BATCH 16
#define OC_TOT 512
#define HH 128
#define WW 128
#define KK 5
#define NOC 32      // output channels per block
#define BROWS 32    // output rows per block (16 row-pairs)
#define NTHREADS 256
#define HW (HH * WW)

typedef float floatx4 __attribute__((ext_vector_type(4)));

// Block: (batch, 32-row tile, 32 ocs). Thread: 2 rows x two dense 4-col quads
// (cols 4j..4j+3 and 64+4j..64+4j+3) = 16 outputs per oc -> tap broadcasts
// amortized 2x vs R5. No register tap array (float4 broadcasts consumed
// directly); dense 256B store runs; nontemporal stores.
__global__ __launch_bounds__(NTHREADS, 2)
void groupconv_kernel(const float* __restrict__ x,
                      const float* __restrict__ weight,
                      const float* __restrict__ bias,
                      float* __restrict__ out)
{
    __shared__ float sIn[BROWS + 4][WW + 4];  // 36 x 132 input tile (zero halo)
    __shared__ float sW[NOC][28];             // 25 taps + bias + 2 pad

    const int tid = threadIdx.x;
    const int bid = blockIdx.x;
    // grid = BATCH * (HH/BROWS) * (OC_TOT/NOC) = 16*4*16 = 1024
    const int octile = bid & 15;
    const int htile  = (bid >> 4) & 3;
    const int b      = bid >> 6;
    const int h0     = htile * BROWS;
    const int ocbase = octile * NOC;

    // ---- stage input tile (zero halo) ----
    const float* xb = x + b * HW;
    for (int idx = tid; idx < (BROWS + 4) * (WW + 4); idx += NTHREADS) {
        int ry = idx / (WW + 4);
        int cx = idx - ry * (WW + 4);
        int gy = h0 - 2 + ry;
        int gx = cx - 2;
        float v = 0.0f;
        if (gy >= 0 && gy < HH && gx >= 0 && gx < WW)
            v = xb[gy * WW + gx];
        sIn[ry][cx] = v;
    }

    // ---- rotated taps for this block's 32 ocs (d=1 -> plane 0 exactly) ----
    for (int idx = tid; idx < NOC * 25; idx += NTHREADS) {
        int i   = idx / 25;
        int t25 = idx - i * 25;
        int ky  = t25 / 5;
        int kx  = t25 - ky * 5;
        int oc  = ocbase + i;
        int o   = oc >> 4;
        int r   = oc & 15;
        const float* wp = weight + o * 25;
        float theta = 0.39269908169872414f * (float)r;   // 2*pi/16 * r
        float cth = cosf(theta), sth = sinf(theta);
        float ty = ((float)ky + 0.5f) * (2.0f / (float)KK) - 1.0f;
        float tx = ((float)kx + 0.5f) * (2.0f / (float)KK) - 1.0f;
        float xi =  cth * tx + sth * ty;
        float yi = -sth * tx + cth * ty;
        float px = (xi + 1.0f) * ((float)KK * 0.5f) - 0.5f;
        float py = (yi + 1.0f) * ((float)KK * 0.5f) - 0.5f;
        float fx0 = floorf(px), fy0 = floorf(py);
        int   x0 = (int)fx0,  y0 = (int)fy0;
        float wx = px - fx0,  wy = py - fy0;
        float v00 = (y0 >= 0   && y0 < KK   && x0 >= 0   && x0 < KK  ) ? wp[y0 * KK + x0]         : 0.0f;
        float v01 = (y0 >= 0   && y0 < KK   && x0+1 >= 0 && x0+1 < KK) ? wp[y0 * KK + x0 + 1]     : 0.0f;
        float v10 = (y0+1 >= 0 && y0+1 < KK && x0 >= 0   && x0 < KK  ) ? wp[(y0+1) * KK + x0]     : 0.0f;
        float v11 = (y0+1 >= 0 && y0+1 < KK && x0+1 >= 0 && x0+1 < KK) ? wp[(y0+1) * KK + x0 + 1] : 0.0f;
        sW[i][t25] = v00 * (1.0f - wy) * (1.0f - wx)
                   + v01 * (1.0f - wy) * wx
                   + v10 * wy * (1.0f - wx)
                   + v11 * wy * wx;
    }
    for (int i = tid; i < NOC * 3; i += NTHREADS) {
        int oc = i / 3, slot = 25 + (i - oc * 3);
        sW[oc][slot] = (slot == 25) ? bias[(ocbase + oc) >> 4] : 0.0f;
    }
    __syncthreads();

    // ---- thread = rows {2p, 2p+1}, cols [4j,4j+3] and [64+4j,64+4j+3] ----
    const int p   = tid >> 4;           // 0..15
    const int j4  = (tid & 15) * 4;     // 0,4,...,60
    const int y0r = h0 + 2 * p;

    // two 6x8 windows in registers (24 ds_read_b128, one-time)
    float winA[6][8], winB[6][8];
#pragma unroll
    for (int r6 = 0; r6 < 6; ++r6) {
        float4 a = *(const float4*)&sIn[2 * p + r6][j4];
        float4 c = *(const float4*)&sIn[2 * p + r6][j4 + 4];
        float4 e = *(const float4*)&sIn[2 * p + r6][64 + j4];
        float4 f = *(const float4*)&sIn[2 * p + r6][64 + j4 + 4];
        winA[r6][0] = a.x; winA[r6][1] = a.y; winA[r6][2] = a.z; winA[r6][3] = a.w;
        winA[r6][4] = c.x; winA[r6][5] = c.y; winA[r6][6] = c.z; winA[r6][7] = c.w;
        winB[r6][0] = e.x; winB[r6][1] = e.y; winB[r6][2] = e.z; winB[r6][3] = e.w;
        winB[r6][4] = f.x; winB[r6][5] = f.y; winB[r6][6] = f.z; winB[r6][7] = f.w;
    }

    float* op = out + ((size_t)b * OC_TOT + ocbase) * (size_t)HW
                    + (size_t)y0r * WW + j4;

#define APPLY(W, KY, KX)                                    \
    a0 = fmaf(winA[KY][(KX)],     (W), a0);                 \
    a1 = fmaf(winA[KY][(KX) + 1], (W), a1);                 \
    a2 = fmaf(winA[KY][(KX) + 2], (W), a2);                 \
    a3 = fmaf(winA[KY][(KX) + 3], (W), a3);                 \
    c0 = fmaf(winA[KY + 1][(KX)],     (W), c0);             \
    c1 = fmaf(winA[KY + 1][(KX) + 1], (W), c1);             \
    c2 = fmaf(winA[KY + 1][(KX) + 2], (W), c2);             \
    c3 = fmaf(winA[KY + 1][(KX) + 3], (W), c3);             \
    b0 = fmaf(winB[KY][(KX)],     (W), b0);                 \
    b1 = fmaf(winB[KY][(KX) + 1], (W), b1);                 \
    b2 = fmaf(winB[KY][(KX) + 2], (W), b2);                 \
    b3 = fmaf(winB[KY][(KX) + 3], (W), b3);                 \
    d0 = fmaf(winB[KY + 1][(KX)],     (W), d0);             \
    d1 = fmaf(winB[KY + 1][(KX) + 1], (W), d1);             \
    d2 = fmaf(winB[KY + 1][(KX) + 2], (W), d2);             \
    d3 = fmaf(winB[KY + 1][(KX) + 3], (W), d3);

    for (int i = 0; i < NOC; ++i) {
        const float4* wrow = (const float4*)&sW[i][0];
        float4 q6 = wrow[6];                 // {tap24, bias, 0, 0}
        float bz = q6.y;
        float a0 = bz, a1 = bz, a2 = bz, a3 = bz;   // row0 quad A
        float c0 = bz, c1 = bz, c2 = bz, c3 = bz;   // row1 quad A
        float b0 = bz, b1 = bz, b2 = bz, b3 = bz;   // row0 quad B
        float d0 = bz, d1 = bz, d2 = bz, d3 = bz;   // row1 quad B
        float4 q;
        q = wrow[0];  APPLY(q.x,0,0) APPLY(q.y,0,1) APPLY(q.z,0,2) APPLY(q.w,0,3)
        q = wrow[1];  APPLY(q.x,0,4) APPLY(q.y,1,0) APPLY(q.z,1,1) APPLY(q.w,1,2)
        q = wrow[2];  APPLY(q.x,1,3) APPLY(q.y,1,4) APPLY(q.z,2,0) APPLY(q.w,2,1)
        q = wrow[3];  APPLY(q.x,2,2) APPLY(q.y,2,3) APPLY(q.z,2,4) APPLY(q.w,3,0)
        q = wrow[4];  APPLY(q.x,3,1) APPLY(q.y,3,2) APPLY(q.z,3,3) APPLY(q.w,3,4)
        q = wrow[5];  APPLY(q.x,4,0) APPLY(q.y,4,1) APPLY(q.z,4,2) APPLY(q.w,4,3)
        APPLY(q6.x,4,4)

        floatx4 va = {a0, a1, a2, a3};
        floatx4 vb = {b0, b1, b2, b3};
        floatx4 vc = {c0, c1, c2, c3};
        floatx4 vd = {d0, d1, d2, d3};
        __builtin_nontemporal_store(va, (floatx4*)op);
        __builtin_nontemporal_store(vb, (floatx4*)(op + 64));
        __builtin_nontemporal_store(vc, (floatx4*)(op + WW));
        __builtin_nontemporal_store(vd, (floatx4*)(op + WW + 64));
        op += HW;
    }
#undef APPLY
}

extern "C" void kernel_launch(void* const* d_in, const int* in_sizes, int n_in,
                              void* d_out, int out_size, void* d_ws, size_t ws_size,
                              hipStream_t stream)
{
    const float* x      = (const float*)d_in[0];  // (16,1,128,128)
    const float* weight = (const float*)d_in[1];  // (32,1,1,5,5)
    const float* bias   = (const float*)d_in[2];  // (32,)
    float* out = (float*)d_out;                   // (16,32,16,128,128)

    const int nblocks = BATCH * (HH / BROWS) * (OC_TOT / NOC);  // 1024
    groupconv_kernel<<<nblocks, NTHREADS, 0, stream>>>(x, weight, bias, out);
}